// Round 2
// baseline (756.380 us; speedup 1.0000x reference)
//
#include <hip/hip_runtime.h>
#include <math.h>

#define NPTS 32768
#define NTYPES 4
#define PER_TYPE 8192
#define HIST 32
#define UD 128
#define XSTR 17   // odd stride: conflict-free scalar LDS transpose access

// ws layout (float offsets):
//   q     [32768][128]      @ 0
//   (unused, was qk)        @ 4194304
//   raw   [32768][32]       @ 8388608
//   Mf    [128]             @ 9437184
//   S     [128]             @ 9437312
//   kT    [4][128][128]     @ 9437440   (k_w transposed per type)
//   wvf   [4][128][128]     @ 9502976   (v_w @ fc_w per type)
//   pm    [4][32][512]      @ 9568512   (per-block online-softmax max)
//   ps    [4][32][512]      @ 9634048   (per-block online-softmax sum)

// ---------------- prep: kT = k_w^T, wvf = v_w @ fc_w -------------------------------
__global__ __launch_bounds__(128) void prep_kernel(
    const float* __restrict__ k_w, const float* __restrict__ v_w,
    const float* __restrict__ fc_w, float* __restrict__ kT,
    float* __restrict__ wvf)
{
    int r = blockIdx.x;   // 0..127 (row of output)
    int t = blockIdx.y;   // type
    int u = threadIdx.x;  // 0..127 (col)
    kT[(t * UD + r) * UD + u] = k_w[(t * UD + u) * UD + r];
    float acc = 0.f;
    const float* vrow = v_w + (t * UD + r) * UD;
    const float* fb = fc_w + t * UD * UD;
    #pragma unroll 8
    for (int m = 0; m < UD; ++m)
        acc = fmaf(vrow[m], fb[m * UD + u], acc);
    wvf[(t * UD + r) * UD + u] = acc;
}

// ---------------- fused: q = x[idx]@q_w ; qk = q@k_w^T ; raw = qk.hist ; (m,s) ------
// 16 entities/block, 2048 blocks. GEMM phases (B,C) of some blocks overlap the
// HBM-stall phase (D) of others; qk never leaves LDS.
__global__ __launch_bounds__(256, 4) void qkr_kernel(
    const float* __restrict__ x, const int* __restrict__ idx,
    const float* __restrict__ q_w, const float* __restrict__ kT,
    const float* __restrict__ hist,
    float* __restrict__ q_out, float* __restrict__ raw,
    float* __restrict__ pm, float* __restrict__ ps)
{
    __shared__ __align__(16) float xT[UD * XSTR];  // A/B: xT[e][ent]; C/D overlay: sqk[16][128]
    __shared__ float qT[UD * XSTR];                // [c][ent]
    __shared__ int srow[16];
    __shared__ float sm[HIST][2], ss[HIST][2];

    int tx = threadIdx.x;
    int bn = blockIdx.x;       // 0..511 -> 16 entities
    int t  = blockIdx.y;
    int n0 = bn * 16;

    if (tx < 16) srow[tx] = idx[t * PER_TYPE + n0 + tx];
    __syncthreads();

    // ---- phase A: gather x rows -> xT[e][ent] (transposed) ----
    {
        int ent = tx & 15;
        int cg  = tx >> 4;        // 0..15, 8 floats each
        const float* xr = x + (size_t)srow[ent] * UD + cg * 8;
        float4 a = *(const float4*)(xr);
        float4 b = *(const float4*)(xr + 4);
        int c0 = cg * 8;
        xT[(c0 + 0) * XSTR + ent] = a.x; xT[(c0 + 1) * XSTR + ent] = a.y;
        xT[(c0 + 2) * XSTR + ent] = a.z; xT[(c0 + 3) * XSTR + ent] = a.w;
        xT[(c0 + 4) * XSTR + ent] = b.x; xT[(c0 + 5) * XSTR + ent] = b.y;
        xT[(c0 + 6) * XSTR + ent] = b.z; xT[(c0 + 7) * XSTR + ent] = b.w;
    }
    __syncthreads();

    const int c4 = (tx & 31) * 4;   // 4 output cols
    const int e2 = (tx >> 5) * 2;   // entity pair base 0,2,..,14
    float acc[2][4];

    // ---- phase B: q[ent][c] = sum_e xT[e][ent] * q_w[e][c] ----
    #pragma unroll
    for (int i = 0; i < 2; ++i)
        #pragma unroll
        for (int j = 0; j < 4; ++j) acc[i][j] = 0.f;
    {
        const float* qw = q_w + t * UD * UD;
        for (int e = 0; e < UD; e += 4) {
            float4 w0 = *(const float4*)(qw + (e + 0) * UD + c4);
            float4 w1 = *(const float4*)(qw + (e + 1) * UD + c4);
            float4 w2 = *(const float4*)(qw + (e + 2) * UD + c4);
            float4 w3 = *(const float4*)(qw + (e + 3) * UD + c4);
            float x00 = xT[(e + 0) * XSTR + e2], x01 = xT[(e + 0) * XSTR + e2 + 1];
            float x10 = xT[(e + 1) * XSTR + e2], x11 = xT[(e + 1) * XSTR + e2 + 1];
            float x20 = xT[(e + 2) * XSTR + e2], x21 = xT[(e + 2) * XSTR + e2 + 1];
            float x30 = xT[(e + 3) * XSTR + e2], x31 = xT[(e + 3) * XSTR + e2 + 1];
            acc[0][0] = fmaf(x00, w0.x, acc[0][0]); acc[0][1] = fmaf(x00, w0.y, acc[0][1]);
            acc[0][2] = fmaf(x00, w0.z, acc[0][2]); acc[0][3] = fmaf(x00, w0.w, acc[0][3]);
            acc[1][0] = fmaf(x01, w0.x, acc[1][0]); acc[1][1] = fmaf(x01, w0.y, acc[1][1]);
            acc[1][2] = fmaf(x01, w0.z, acc[1][2]); acc[1][3] = fmaf(x01, w0.w, acc[1][3]);
            acc[0][0] = fmaf(x10, w1.x, acc[0][0]); acc[0][1] = fmaf(x10, w1.y, acc[0][1]);
            acc[0][2] = fmaf(x10, w1.z, acc[0][2]); acc[0][3] = fmaf(x10, w1.w, acc[0][3]);
            acc[1][0] = fmaf(x11, w1.x, acc[1][0]); acc[1][1] = fmaf(x11, w1.y, acc[1][1]);
            acc[1][2] = fmaf(x11, w1.z, acc[1][2]); acc[1][3] = fmaf(x11, w1.w, acc[1][3]);
            acc[0][0] = fmaf(x20, w2.x, acc[0][0]); acc[0][1] = fmaf(x20, w2.y, acc[0][1]);
            acc[0][2] = fmaf(x20, w2.z, acc[0][2]); acc[0][3] = fmaf(x20, w2.w, acc[0][3]);
            acc[1][0] = fmaf(x21, w2.x, acc[1][0]); acc[1][1] = fmaf(x21, w2.y, acc[1][1]);
            acc[1][2] = fmaf(x21, w2.z, acc[1][2]); acc[1][3] = fmaf(x21, w2.w, acc[1][3]);
            acc[0][0] = fmaf(x30, w3.x, acc[0][0]); acc[0][1] = fmaf(x30, w3.y, acc[0][1]);
            acc[0][2] = fmaf(x30, w3.z, acc[0][2]); acc[0][3] = fmaf(x30, w3.w, acc[0][3]);
            acc[1][0] = fmaf(x31, w3.x, acc[1][0]); acc[1][1] = fmaf(x31, w3.y, acc[1][1]);
            acc[1][2] = fmaf(x31, w3.z, acc[1][2]); acc[1][3] = fmaf(x31, w3.w, acc[1][3]);
        }
    }
    // write q to global; qT (transposed) to LDS
    #pragma unroll
    for (int i = 0; i < 2; ++i) {
        int g = t * PER_TYPE + n0 + e2 + i;
        *(float4*)(q_out + (size_t)g * UD + c4) =
            make_float4(acc[i][0], acc[i][1], acc[i][2], acc[i][3]);
    }
    #pragma unroll
    for (int j = 0; j < 4; ++j) {
        qT[(c4 + j) * XSTR + e2]     = acc[0][j];
        qT[(c4 + j) * XSTR + e2 + 1] = acc[1][j];
    }
    __syncthreads();

    // ---- phase C: qk[ent][u] = sum_v qT[v][ent] * kT[v][u] -> sqk (overlay on xT) ----
    float* sqk = xT;   // xT dead after phase B; 16*128 = 2048 <= 128*17 floats
    #pragma unroll
    for (int i = 0; i < 2; ++i)
        #pragma unroll
        for (int j = 0; j < 4; ++j) acc[i][j] = 0.f;
    {
        const float* kw = kT + t * UD * UD;
        for (int v = 0; v < UD; v += 4) {
            float4 w0 = *(const float4*)(kw + (v + 0) * UD + c4);
            float4 w1 = *(const float4*)(kw + (v + 1) * UD + c4);
            float4 w2 = *(const float4*)(kw + (v + 2) * UD + c4);
            float4 w3 = *(const float4*)(kw + (v + 3) * UD + c4);
            float x00 = qT[(v + 0) * XSTR + e2], x01 = qT[(v + 0) * XSTR + e2 + 1];
            float x10 = qT[(v + 1) * XSTR + e2], x11 = qT[(v + 1) * XSTR + e2 + 1];
            float x20 = qT[(v + 2) * XSTR + e2], x21 = qT[(v + 2) * XSTR + e2 + 1];
            float x30 = qT[(v + 3) * XSTR + e2], x31 = qT[(v + 3) * XSTR + e2 + 1];
            acc[0][0] = fmaf(x00, w0.x, acc[0][0]); acc[0][1] = fmaf(x00, w0.y, acc[0][1]);
            acc[0][2] = fmaf(x00, w0.z, acc[0][2]); acc[0][3] = fmaf(x00, w0.w, acc[0][3]);
            acc[1][0] = fmaf(x01, w0.x, acc[1][0]); acc[1][1] = fmaf(x01, w0.y, acc[1][1]);
            acc[1][2] = fmaf(x01, w0.z, acc[1][2]); acc[1][3] = fmaf(x01, w0.w, acc[1][3]);
            acc[0][0] = fmaf(x10, w1.x, acc[0][0]); acc[0][1] = fmaf(x10, w1.y, acc[0][1]);
            acc[0][2] = fmaf(x10, w1.z, acc[0][2]); acc[0][3] = fmaf(x10, w1.w, acc[0][3]);
            acc[1][0] = fmaf(x11, w1.x, acc[1][0]); acc[1][1] = fmaf(x11, w1.y, acc[1][1]);
            acc[1][2] = fmaf(x11, w1.z, acc[1][2]); acc[1][3] = fmaf(x11, w1.w, acc[1][3]);
            acc[0][0] = fmaf(x20, w2.x, acc[0][0]); acc[0][1] = fmaf(x20, w2.y, acc[0][1]);
            acc[0][2] = fmaf(x20, w2.z, acc[0][2]); acc[0][3] = fmaf(x20, w2.w, acc[0][3]);
            acc[1][0] = fmaf(x21, w2.x, acc[1][0]); acc[1][1] = fmaf(x21, w2.y, acc[1][1]);
            acc[1][2] = fmaf(x21, w2.z, acc[1][2]); acc[1][3] = fmaf(x21, w2.w, acc[1][3]);
            acc[0][0] = fmaf(x30, w3.x, acc[0][0]); acc[0][1] = fmaf(x30, w3.y, acc[0][1]);
            acc[0][2] = fmaf(x30, w3.z, acc[0][2]); acc[0][3] = fmaf(x30, w3.w, acc[0][3]);
            acc[1][0] = fmaf(x31, w3.x, acc[1][0]); acc[1][1] = fmaf(x31, w3.y, acc[1][1]);
            acc[1][2] = fmaf(x31, w3.z, acc[1][2]); acc[1][3] = fmaf(x31, w3.w, acc[1][3]);
        }
    }
    __syncthreads();   // xT reads done everywhere before overlay writes
    #pragma unroll
    for (int i = 0; i < 2; ++i)
        *(float4*)(&sqk[(e2 + i) * UD + c4]) =
            make_float4(acc[i][0], acc[i][1], acc[i][2], acc[i][3]);
    __syncthreads();

    // ---- phase D: raw[n][h] = sqk[n] . hist[row[n]][h], online (m,s) ----
    int sub = tx & 3;          // 32-float chunk of the 128-dot
    int hh  = (tx >> 2) & 31;  // history row
    int eh  = tx >> 7;         // 0/1
    float m = -INFINITY, s = 0.f;
    for (int j = 0; j < 8; ++j) {
        int ei = j * 2 + eh;
        int g  = t * PER_TYPE + n0 + ei;
        const float* hr = hist + ((size_t)srow[ei] * HIST + hh) * UD + sub * 32;
        float4 h0 = *(const float4*)(hr);
        float4 h1 = *(const float4*)(hr + 4);
        float4 h2 = *(const float4*)(hr + 8);
        float4 h3 = *(const float4*)(hr + 12);
        float4 h4 = *(const float4*)(hr + 16);
        float4 h5 = *(const float4*)(hr + 20);
        float4 h6 = *(const float4*)(hr + 24);
        float4 h7 = *(const float4*)(hr + 28);
        const float* qr = &sqk[ei * UD + sub * 32];
        float4 q0 = *(const float4*)(qr);
        float4 q1 = *(const float4*)(qr + 4);
        float4 q2 = *(const float4*)(qr + 8);
        float4 q3 = *(const float4*)(qr + 12);
        float4 q4 = *(const float4*)(qr + 16);
        float4 q5 = *(const float4*)(qr + 20);
        float4 q6 = *(const float4*)(qr + 24);
        float4 q7 = *(const float4*)(qr + 28);
        float p0 = q0.x * h0.x + q0.y * h0.y + q0.z * h0.z + q0.w * h0.w;
        float p1 = q1.x * h1.x + q1.y * h1.y + q1.z * h1.z + q1.w * h1.w;
        float p2 = q2.x * h2.x + q2.y * h2.y + q2.z * h2.z + q2.w * h2.w;
        float p3 = q3.x * h3.x + q3.y * h3.y + q3.z * h3.z + q3.w * h3.w;
        p0 = fmaf(q4.x, h4.x, fmaf(q4.y, h4.y, fmaf(q4.z, h4.z, fmaf(q4.w, h4.w, p0))));
        p1 = fmaf(q5.x, h5.x, fmaf(q5.y, h5.y, fmaf(q5.z, h5.z, fmaf(q5.w, h5.w, p1))));
        p2 = fmaf(q6.x, h6.x, fmaf(q6.y, h6.y, fmaf(q6.z, h6.z, fmaf(q6.w, h6.w, p2))));
        p3 = fmaf(q7.x, h7.x, fmaf(q7.y, h7.y, fmaf(q7.z, h7.z, fmaf(q7.w, h7.w, p3))));
        float a = (p0 + p1) + (p2 + p3);
        a += __shfl_xor(a, 1);
        a += __shfl_xor(a, 2);
        if (sub == 0) raw[(size_t)g * HIST + hh] = a;
        float mo = m;
        m = fmaxf(m, a);
        s = s * __expf(mo - m) + __expf(a - m);
    }
    if (sub == 0) { sm[hh][eh] = m; ss[hh][eh] = s; }
    __syncthreads();
    if (tx < HIST) {
        float m0 = sm[tx][0], m1 = sm[tx][1];
        float M = fmaxf(m0, m1);
        float Sv = ss[tx][0] * __expf(m0 - M) + ss[tx][1] * __expf(m1 - M);
        pm[((size_t)t * HIST + tx) * 512 + bn] = M;
        ps[((size_t)t * HIST + tx) * 512 + bn] = Sv;
    }
}

// ---------------- merge 512 per-block (m,s) partials -> Mf[t][h], S[t][h] ----------
__global__ __launch_bounds__(256) void merge_kernel(
    const float* __restrict__ pm, const float* __restrict__ ps,
    float* __restrict__ Mf, float* __restrict__ S)
{
    int b = blockIdx.x;   // 0..127 = t*32+h
    int tx = threadIdx.x;
    float m = -INFINITY, s = 0.f;
    #pragma unroll
    for (int i = 0; i < 2; ++i) {
        int k = tx + i * 256;
        float pmv = pm[(size_t)b * 512 + k];
        float psv = ps[(size_t)b * 512 + k];
        float M = fmaxf(m, pmv);
        s = s * expf(m - M) + psv * expf(pmv - M);
        m = M;
    }
    #pragma unroll
    for (int off = 1; off < 64; off <<= 1) {
        float om = __shfl_xor(m, off);
        float os = __shfl_xor(s, off);
        float M = fmaxf(m, om);
        s = s * expf(m - M) + os * expf(om - M);
        m = M;
    }
    __shared__ float rm[4], rs[4];
    int wave = tx >> 6, lane = tx & 63;
    if (lane == 0) { rm[wave] = m; rs[wave] = s; }
    __syncthreads();
    if (tx == 0) {
        float M = fmaxf(fmaxf(rm[0], rm[1]), fmaxf(rm[2], rm[3]));
        float Sv = rs[0] * expf(rm[0] - M) + rs[1] * expf(rm[1] - M)
                 + rs[2] * expf(rm[2] - M) + rs[3] * expf(rm[3] - M);
        Mf[b] = M;
        S[b] = Sv;
    }
}

// ---------------- out: fast path out=q; slow path gather active h rows --------------
__global__ __launch_bounds__(256) void out_kernel(
    const float* __restrict__ hist, const int* __restrict__ idx,
    const float* __restrict__ q, const float* __restrict__ raw,
    const float* __restrict__ Mf, const float* __restrict__ S,
    const float* __restrict__ wvf, float* __restrict__ out)
{
    __shared__ float shbar[4][UD];
    int tx = threadIdx.x;
    int wave = tx >> 6;
    int lane = tx & 63;
    int g = blockIdx.x * 4 + wave;   // global entity 0..32767
    int t = g >> 13;                 // /8192
    float w = 0.f;
    if (lane < 32) {
        float r = raw[(size_t)g * HIST + lane];
        float M = Mf[t * HIST + lane];
        float e = r - M;
        if (e > -75.f) w = expf(e) / S[t * HIST + lane];  // skipped terms < 3e-33
    }
    unsigned long long act = __ballot(w != 0.f);
    int u2 = lane * 2;
    float2 qv = *(const float2*)(q + (size_t)g * UD + u2);
    float2 o;
    if (act == 0ull) {
        o = qv;  // all attention weights exactly 0 -> relu(0) + q
    } else {
        int row = idx[g];
        float2 hb = make_float2(0.f, 0.f);
        unsigned long long m = act;
        while (m) {
            int hh = __ffsll(m) - 1;
            m &= m - 1;
            float wv = __shfl(w, hh);
            float2 hv = *(const float2*)(hist + ((size_t)row * HIST + hh) * UD + u2);
            hb.x = fmaf(wv, hv.x, hb.x);
            hb.y = fmaf(wv, hv.y, hb.y);
        }
        shbar[wave][u2] = hb.x;
        shbar[wave][u2 + 1] = hb.y;
        float2 a = make_float2(0.f, 0.f);
        const float* wt = wvf + t * UD * UD;
        for (int e = 0; e < UD; ++e) {
            float hbe = shbar[wave][e];
            float2 wr = *(const float2*)(wt + e * UD + u2);
            a.x = fmaf(hbe, wr.x, a.x);
            a.y = fmaf(hbe, wr.y, a.y);
        }
        o.x = fmaxf(a.x, 0.f) + qv.x;
        o.y = fmaxf(a.y, 0.f) + qv.y;
    }
    *(float2*)(out + (size_t)g * UD + u2) = o;
}

extern "C" void kernel_launch(void* const* d_in, const int* in_sizes, int n_in,
                              void* d_out, int out_size, void* d_ws, size_t ws_size,
                              hipStream_t stream) {
    const float* x    = (const float*)d_in[0];
    const float* hist = (const float*)d_in[1];
    const int*   idx  = (const int*)d_in[2];
    const float* q_w  = (const float*)d_in[3];
    const float* k_w  = (const float*)d_in[4];
    const float* v_w  = (const float*)d_in[5];
    const float* fc_w = (const float*)d_in[6];
    float* out = (float*)d_out;

    float* ws = (float*)d_ws;
    float* q     = ws;
    float* raw   = ws + 8388608;
    float* Mf    = ws + 9437184;
    float* S     = ws + 9437312;
    float* kT    = ws + 9437440;
    float* wvf   = ws + 9502976;
    float* pm    = ws + 9568512;
    float* ps    = ws + 9634048;

    prep_kernel<<<dim3(128, 4), 128, 0, stream>>>(k_w, v_w, fc_w, kT, wvf);
    qkr_kernel<<<dim3(512, 4), 256, 0, stream>>>(x, idx, q_w, kT, hist, q, raw, pm, ps);
    merge_kernel<<<128, 256, 0, stream>>>(pm, ps, Mf, S);
    out_kernel<<<8192, 256, 0, stream>>>(hist, idx, q, raw, Mf, S, wvf, out);
}

// Round 3
// 747.200 us; speedup vs baseline: 1.0123x; 1.0123x over previous
//
#include <hip/hip_runtime.h>
#include <math.h>

#define NPTS 32768
#define NTYPES 4
#define PER_TYPE 8192
#define HIST 32
#define UD 128
#define XT_STRIDE 36   // 32-entity tiles +4 pad: 144B row pitch, 16B-aligned for b128

// ws layout (float offsets):
//   q     [32768][128]      @ 0
//   qk    [32768][128]      @ 4194304
//   raw   [32768][32]       @ 8388608
//   Mf    [128]             @ 9437184
//   S     [128]             @ 9437312
//   kT    [4][128][128]     @ 9437440   (k_w transposed per type)
//   wvf   [4][128][128]     @ 9502976   (v_w @ fc_w per type)
//   pm    [4][32][512]      @ 9568512   (per-block online-softmax max)
//   ps    [4][32][512]      @ 9634048   (per-block online-softmax sum)
// total 9699584 floats = 38.8 MB

// ---------------- prep: kT = k_w^T, wvf = v_w @ fc_w -------------------------------
__global__ __launch_bounds__(128) void prep_kernel(
    const float* __restrict__ k_w, const float* __restrict__ v_w,
    const float* __restrict__ fc_w, float* __restrict__ kT,
    float* __restrict__ wvf)
{
    int r = blockIdx.x;   // 0..127 (row of output)
    int t = blockIdx.y;   // type
    int u = threadIdx.x;  // 0..127 (col)
    // kT[t][r][u] = k_w[t][u][r]
    kT[(t * UD + r) * UD + u] = k_w[(t * UD + u) * UD + r];
    // wvf[t][r][u] = sum_m v_w[t][r][m] * fc_w[t][m][u]
    float acc = 0.f;
    const float* vrow = v_w + (t * UD + r) * UD;
    const float* fb = fc_w + t * UD * UD;
    #pragma unroll 8
    for (int m = 0; m < UD; ++m)
        acc = fmaf(vrow[m], fb[m * UD + u], acc);
    wvf[(t * UD + r) * UD + u] = acc;
}

// ---------------- q = x[idx] @ q_w ; qk = q @ k_w^T  (32 entities/block) ------------
__global__ __launch_bounds__(256) void qqk_kernel(
    const float* __restrict__ x, const int* __restrict__ idx,
    const float* __restrict__ q_w, const float* __restrict__ kT,
    float* __restrict__ q_out, float* __restrict__ qk_out)
{
    __shared__ float xT[UD * XT_STRIDE];  // [e][ent], padded
    __shared__ float qT[UD * XT_STRIDE];  // [c][ent], padded
    __shared__ int srow[32];
    int tx = threadIdx.x;
    int bn = blockIdx.x;      // 0..255 -> 32 entities
    int t  = blockIdx.y;
    int n0 = bn * 32;

    if (tx < 32) srow[tx] = idx[t * PER_TYPE + n0 + tx];
    __syncthreads();

    // load x transposed into LDS: xT[e][ent]
    {
        int e = tx & 127;
        int half = tx >> 7;
        for (int i = 0; i < 16; ++i) {
            int ent = half * 16 + i;
            xT[e * XT_STRIDE + ent] = x[(size_t)srow[ent] * UD + e];
        }
    }
    __syncthreads();

    const int c4 = (tx & 31) * 4;  // 4 output cols
    const int eg = tx >> 5;        // 0..7 -> 4 entities eg*4..eg*4+3
    float acc[4][4];

    // phase 1: q[ent][c] = sum_e xT[e][ent] * q_w[e][c]
    #pragma unroll
    for (int i = 0; i < 4; ++i)
        #pragma unroll
        for (int j = 0; j < 4; ++j) acc[i][j] = 0.f;
    {
        const float* qw = q_w + t * UD * UD;
        for (int e = 0; e < UD; ++e) {
            float4 w = *(const float4*)(qw + e * UD + c4);
            float4 a0 = *(const float4*)(&xT[e * XT_STRIDE + eg * 4]);
            float av[4] = {a0.x, a0.y, a0.z, a0.w};
            #pragma unroll
            for (int i = 0; i < 4; ++i) {
                acc[i][0] = fmaf(av[i], w.x, acc[i][0]);
                acc[i][1] = fmaf(av[i], w.y, acc[i][1]);
                acc[i][2] = fmaf(av[i], w.z, acc[i][2]);
                acc[i][3] = fmaf(av[i], w.w, acc[i][3]);
            }
        }
    }
    // write q to global + qT (transposed) to LDS
    #pragma unroll
    for (int i = 0; i < 4; ++i) {
        int g = t * PER_TYPE + n0 + eg * 4 + i;
        *(float4*)(q_out + (size_t)g * UD + c4) =
            make_float4(acc[i][0], acc[i][1], acc[i][2], acc[i][3]);
    }
    #pragma unroll
    for (int j = 0; j < 4; ++j) {
        *(float4*)(&qT[(c4 + j) * XT_STRIDE + eg * 4]) =
            make_float4(acc[0][j], acc[1][j], acc[2][j], acc[3][j]);
    }
    __syncthreads();

    // phase 2: qk[ent][u] = sum_v qT[v][ent] * kT[t][v][u]
    #pragma unroll
    for (int i = 0; i < 4; ++i)
        #pragma unroll
        for (int j = 0; j < 4; ++j) acc[i][j] = 0.f;
    {
        const float* kw = kT + t * UD * UD;
        for (int v = 0; v < UD; ++v) {
            float4 w = *(const float4*)(kw + v * UD + c4);
            float4 a0 = *(const float4*)(&qT[v * XT_STRIDE + eg * 4]);
            float av[4] = {a0.x, a0.y, a0.z, a0.w};
            #pragma unroll
            for (int i = 0; i < 4; ++i) {
                acc[i][0] = fmaf(av[i], w.x, acc[i][0]);
                acc[i][1] = fmaf(av[i], w.y, acc[i][1]);
                acc[i][2] = fmaf(av[i], w.z, acc[i][2]);
                acc[i][3] = fmaf(av[i], w.w, acc[i][3]);
            }
        }
    }
    #pragma unroll
    for (int i = 0; i < 4; ++i) {
        int g = t * PER_TYPE + n0 + eg * 4 + i;
        *(float4*)(qk_out + (size_t)g * UD + c4) =
            make_float4(acc[i][0], acc[i][1], acc[i][2], acc[i][3]);
    }
}

// ---------------- raw[n][h] = hist[idx[n]][h] . qk[n]  + per-block online (m,s) -----
// online softmax per lane (8 entities) -> block-level (m,s) partials to global.
__global__ __launch_bounds__(256) void raw_kernel(
    const float* __restrict__ hist, const int* __restrict__ idx,
    const float* __restrict__ qk, float* __restrict__ raw,
    float* __restrict__ pm, float* __restrict__ ps)
{
    __shared__ int srow[16];
    __shared__ float sqk[16 * UD];
    __shared__ float sm[HIST][2];
    __shared__ float ss[HIST][2];
    int tx = threadIdx.x;
    int bn = blockIdx.x;       // 0..511 -> 16 entities
    int t  = blockIdx.y;
    int n0 = bn * 16;
    if (tx < 16) srow[tx] = idx[t * PER_TYPE + n0 + tx];
    {   // stage 16 qk rows (8 KB) into LDS, coalesced
        int e = tx >> 4;          // entity 0..15
        int c = (tx & 15) * 8;    // col 0..120
        const float* src = qk + ((size_t)(t * PER_TYPE + n0 + e)) * UD + c;
        float4 a = *(const float4*)(src);
        float4 b = *(const float4*)(src + 4);
        *(float4*)(&sqk[e * UD + c]) = a;
        *(float4*)(&sqk[e * UD + c + 4]) = b;
    }
    __syncthreads();

    int sub = tx & 3;          // which 32-float chunk of the 128-dot
    int hh  = (tx >> 2) & 31;  // history row
    int eh  = tx >> 7;         // 0/1: which entity of the current pair
    float m = -INFINITY, s = 0.f;
    for (int j = 0; j < 8; ++j) {
        int ei = j * 2 + eh;
        int g  = t * PER_TYPE + n0 + ei;
        const float* hr = hist + ((size_t)srow[ei] * HIST + hh) * UD + sub * 32;
        // 8 independent global loads issued before any use
        float4 h0 = *(const float4*)(hr);
        float4 h1 = *(const float4*)(hr + 4);
        float4 h2 = *(const float4*)(hr + 8);
        float4 h3 = *(const float4*)(hr + 12);
        float4 h4 = *(const float4*)(hr + 16);
        float4 h5 = *(const float4*)(hr + 20);
        float4 h6 = *(const float4*)(hr + 24);
        float4 h7 = *(const float4*)(hr + 28);
        const float* qr = &sqk[ei * UD + sub * 32];
        float4 q0 = *(const float4*)(qr);
        float4 q1 = *(const float4*)(qr + 4);
        float4 q2 = *(const float4*)(qr + 8);
        float4 q3 = *(const float4*)(qr + 12);
        float4 q4 = *(const float4*)(qr + 16);
        float4 q5 = *(const float4*)(qr + 20);
        float4 q6 = *(const float4*)(qr + 24);
        float4 q7 = *(const float4*)(qr + 28);
        // 4 independent partial chains
        float p0 = q0.x * h0.x + q0.y * h0.y + q0.z * h0.z + q0.w * h0.w;
        float p1 = q1.x * h1.x + q1.y * h1.y + q1.z * h1.z + q1.w * h1.w;
        float p2 = q2.x * h2.x + q2.y * h2.y + q2.z * h2.z + q2.w * h2.w;
        float p3 = q3.x * h3.x + q3.y * h3.y + q3.z * h3.z + q3.w * h3.w;
        p0 = fmaf(q4.x, h4.x, fmaf(q4.y, h4.y, fmaf(q4.z, h4.z, fmaf(q4.w, h4.w, p0))));
        p1 = fmaf(q5.x, h5.x, fmaf(q5.y, h5.y, fmaf(q5.z, h5.z, fmaf(q5.w, h5.w, p1))));
        p2 = fmaf(q6.x, h6.x, fmaf(q6.y, h6.y, fmaf(q6.z, h6.z, fmaf(q6.w, h6.w, p2))));
        p3 = fmaf(q7.x, h7.x, fmaf(q7.y, h7.y, fmaf(q7.z, h7.z, fmaf(q7.w, h7.w, p3))));
        float a = (p0 + p1) + (p2 + p3);
        a += __shfl_xor(a, 1);
        a += __shfl_xor(a, 2);
        if (sub == 0) raw[(size_t)g * HIST + hh] = a;
        // online softmax update (all 4 sub lanes redundantly; hidden under vmcnt waits)
        float mo = m;
        m = fmaxf(m, a);
        s = s * __expf(mo - m) + __expf(a - m);
    }
    if (sub == 0) { sm[hh][eh] = m; ss[hh][eh] = s; }  // unique (hh,eh) per writer
    __syncthreads();
    if (tx < HIST) {
        float m0 = sm[tx][0], m1 = sm[tx][1];
        float M = fmaxf(m0, m1);
        float S = ss[tx][0] * __expf(m0 - M) + ss[tx][1] * __expf(m1 - M);
        pm[((size_t)t * HIST + tx) * 512 + bn] = M;
        ps[((size_t)t * HIST + tx) * 512 + bn] = S;
    }
}

// ---------------- merge 512 per-block (m,s) partials -> Mf[t][h], S[t][h] ----------
__global__ __launch_bounds__(256) void merge_kernel(
    const float* __restrict__ pm, const float* __restrict__ ps,
    float* __restrict__ Mf, float* __restrict__ S)
{
    int b = blockIdx.x;   // 0..127 = t*32+h
    int tx = threadIdx.x;
    float m = -INFINITY, s = 0.f;
    #pragma unroll
    for (int i = 0; i < 2; ++i) {
        int k = tx + i * 256;
        float pmv = pm[(size_t)b * 512 + k];
        float psv = ps[(size_t)b * 512 + k];
        float M = fmaxf(m, pmv);
        s = s * expf(m - M) + psv * expf(pmv - M);
        m = M;
    }
    #pragma unroll
    for (int off = 1; off < 64; off <<= 1) {
        float om = __shfl_xor(m, off);
        float os = __shfl_xor(s, off);
        float M = fmaxf(m, om);
        s = s * expf(m - M) + os * expf(om - M);
        m = M;
    }
    __shared__ float rm[4], rs[4];
    int wave = tx >> 6, lane = tx & 63;
    if (lane == 0) { rm[wave] = m; rs[wave] = s; }
    __syncthreads();
    if (tx == 0) {
        float M = fmaxf(fmaxf(rm[0], rm[1]), fmaxf(rm[2], rm[3]));
        float Sv = rs[0] * expf(rm[0] - M) + rs[1] * expf(rm[1] - M)
                 + rs[2] * expf(rm[2] - M) + rs[3] * expf(rm[3] - M);
        Mf[b] = M;
        S[b] = Sv;
    }
}

// ---------------- out: fast path out=q; slow path gather active h rows --------------
__global__ __launch_bounds__(256) void out_kernel(
    const float* __restrict__ hist, const int* __restrict__ idx,
    const float* __restrict__ q, const float* __restrict__ raw,
    const float* __restrict__ Mf, const float* __restrict__ S,
    const float* __restrict__ wvf, float* __restrict__ out)
{
    __shared__ float shbar[4][UD];
    int tx = threadIdx.x;
    int wave = tx >> 6;
    int lane = tx & 63;
    int g = blockIdx.x * 4 + wave;   // global entity 0..32767
    int t = g >> 13;                 // /8192
    float w = 0.f;
    if (lane < 32) {
        float r = raw[(size_t)g * HIST + lane];
        float M = Mf[t * HIST + lane];
        float e = r - M;
        if (e > -75.f) w = expf(e) / S[t * HIST + lane];  // skipped terms < 3e-33
    }
    unsigned long long act = __ballot(w != 0.f);
    int u2 = lane * 2;
    float2 qv = *(const float2*)(q + (size_t)g * UD + u2);
    float2 o;
    if (act == 0ull) {
        o = qv;  // all attention weights exactly 0 -> relu(0) + q
    } else {
        int row = idx[g];
        float2 hb = make_float2(0.f, 0.f);
        unsigned long long m = act;
        while (m) {
            int hh = __ffsll(m) - 1;
            m &= m - 1;
            float wv = __shfl(w, hh);
            float2 hv = *(const float2*)(hist + ((size_t)row * HIST + hh) * UD + u2);
            hb.x = fmaf(wv, hv.x, hb.x);
            hb.y = fmaf(wv, hv.y, hb.y);
        }
        // wave-local LDS round trip (no barrier needed within one wave)
        shbar[wave][u2] = hb.x;
        shbar[wave][u2 + 1] = hb.y;
        float2 a = make_float2(0.f, 0.f);
        const float* wt = wvf + t * UD * UD;
        for (int e = 0; e < UD; ++e) {
            float hbe = shbar[wave][e];
            float2 wr = *(const float2*)(wt + e * UD + u2);
            a.x = fmaf(hbe, wr.x, a.x);
            a.y = fmaf(hbe, wr.y, a.y);
        }
        o.x = fmaxf(a.x, 0.f) + qv.x;
        o.y = fmaxf(a.y, 0.f) + qv.y;
    }
    *(float2*)(out + (size_t)g * UD + u2) = o;
}

extern "C" void kernel_launch(void* const* d_in, const int* in_sizes, int n_in,
                              void* d_out, int out_size, void* d_ws, size_t ws_size,
                              hipStream_t stream) {
    const float* x    = (const float*)d_in[0];
    const float* hist = (const float*)d_in[1];
    const int*   idx  = (const int*)d_in[2];
    const float* q_w  = (const float*)d_in[3];
    const float* k_w  = (const float*)d_in[4];
    const float* v_w  = (const float*)d_in[5];
    const float* fc_w = (const float*)d_in[6];
    float* out = (float*)d_out;

    float* ws = (float*)d_ws;
    float* q     = ws;
    float* qk    = ws + 4194304;
    float* raw   = ws + 8388608;
    float* Mf    = ws + 9437184;
    float* S     = ws + 9437312;
    float* kT    = ws + 9437440;
    float* wvf   = ws + 9502976;
    float* pm    = ws + 9568512;
    float* ps    = ws + 9634048;

    prep_kernel<<<dim3(128, 4), 128, 0, stream>>>(k_w, v_w, fc_w, kT, wvf);
    qqk_kernel<<<dim3(256, 4), 256, 0, stream>>>(x, idx, q_w, kT, q, qk);
    raw_kernel<<<dim3(512, 4), 256, 0, stream>>>(hist, idx, qk, raw, pm, ps);
    merge_kernel<<<128, 256, 0, stream>>>(pm, ps, Mf, S);
    out_kernel<<<8192, 256, 0, stream>>>(hist, idx, q, raw, Mf, S, wvf, out);
}